// Round 3
// baseline (1372.635 us; speedup 1.0000x reference)
//
#include <hip/hip_runtime.h>
#include <hip/hip_bf16.h>

// Problem constants (B,T,C,H,DH) = (2,2048,768,12,64)
#define Bn 2
#define Tn 2048
#define Cn 768
#define Hn 12
#define Dn 64
#define N3n 2304
#define Mn 4096   // B*T

#define MASKVAL (-30000.f)   // finite sentinel; scores are O(+-15)

typedef unsigned short u16;

__device__ __forceinline__ float bf2f(u16 u) {
  union { unsigned int i; float f; } v; v.i = ((unsigned int)u) << 16; return v.f;
}
__device__ __forceinline__ u16 f2bf(float f) {
  union { float f; unsigned int i; } v; v.f = f;
  return (u16)((v.i + 0x7fffu + ((v.i >> 16) & 1u)) >> 16);
}
__device__ __forceinline__ float safe_exp(float x) {
  return __expf(fmaxf(x, -80.f));   // arg in [-80,0]; never inf/NaN
}

// 4-wide load/store, overloaded on intermediate dtype (fp32 or bf16)
__device__ __forceinline__ float4 load4(const float* p) { return *(const float4*)p; }
__device__ __forceinline__ float4 load4(const u16* p) {
  ushort4 q = *(const ushort4*)p;
  return make_float4(bf2f(q.x), bf2f(q.y), bf2f(q.z), bf2f(q.w));
}
__device__ __forceinline__ void store4(float* p, float a, float b, float c, float d) {
  *(float4*)p = make_float4(a, b, c, d);
}
__device__ __forceinline__ void store4(u16* p, float a, float b, float c, float d) {
  ushort4 s; s.x = f2bf(a); s.y = f2bf(b); s.z = f2bf(c); s.w = f2bf(d);
  *(ushort4*)p = s;
}

// ---------------------------------------------------------------------------
// Kernel 1: QKV projection. x[4096,768]fp32 @ Wqkv[768,2304]fp32 -> Q,K,V (WT)
// 64x64 tile, BK=16, 16x16 threads, 4x4 acc/thread, fp32 math.
// ---------------------------------------------------------------------------
template <typename WT>
__global__ __launch_bounds__(256) void qkv_gemm(const float* __restrict__ x,
                                                const float* __restrict__ w,
                                                WT* __restrict__ Q,
                                                WT* __restrict__ K,
                                                WT* __restrict__ V) {
  __shared__ float As[16 * 68];  // [kk][row], pad 68 vs bank conflicts
  __shared__ float Bs[16 * 68];  // [kk][col]
  const int tx = threadIdx.x, ty = threadIdx.y;
  const int tid = ty * 16 + tx;
  const int n0 = blockIdx.x * 64;
  const int m0 = blockIdx.y * 64;

  float acc[4][4] = {};

  for (int k0 = 0; k0 < Cn; k0 += 16) {
    __syncthreads();
    {
      const int row = tid >> 2, kkb = (tid & 3) << 2;
      float4 qa = *(const float4*)(x + (m0 + row) * Cn + k0 + kkb);
      As[(kkb + 0) * 68 + row] = qa.x;
      As[(kkb + 1) * 68 + row] = qa.y;
      As[(kkb + 2) * 68 + row] = qa.z;
      As[(kkb + 3) * 68 + row] = qa.w;
      const int kk = tid >> 4, colb = (tid & 15) << 2;
      float4 qb = *(const float4*)(w + (k0 + kk) * N3n + n0 + colb);
      Bs[kk * 68 + colb + 0] = qb.x;
      Bs[kk * 68 + colb + 1] = qb.y;
      Bs[kk * 68 + colb + 2] = qb.z;
      Bs[kk * 68 + colb + 3] = qb.w;
    }
    __syncthreads();
#pragma unroll
    for (int kk = 0; kk < 16; kk++) {
      float4 a4 = *(const float4*)(As + kk * 68 + ty * 4);
      float4 b4 = *(const float4*)(Bs + kk * 68 + tx * 4);
      float a[4] = {a4.x, a4.y, a4.z, a4.w};
      float b[4] = {b4.x, b4.y, b4.z, b4.w};
#pragma unroll
      for (int i = 0; i < 4; i++)
#pragma unroll
        for (int j = 0; j < 4; j++) acc[i][j] += a[i] * b[j];
    }
  }

  const int which = n0 / Cn;          // uniform per block (768 % 64 == 0)
  const int c0 = n0 - which * Cn;
  const int h = c0 >> 6;              // uniform per block
  WT* dst = (which == 0) ? Q : ((which == 1) ? K : V);
#pragma unroll
  for (int i = 0; i < 4; i++) {
    const int m = m0 + ty * 4 + i;
    const int b = m >> 11, t = m & (Tn - 1);
    store4(dst + (((b * Hn + h) * Tn + t) * Dn) + tx * 4,
           acc[i][0], acc[i][1], acc[i][2], acc[i][3]);
  }
}

// ---------------------------------------------------------------------------
// Kernel 2: causal flash attention, fp32 math, WT I/O. Inf-free by design.
// One block per (q-tile of 64 rows, h, b). Br=64, Bc=32, online softmax.
// ---------------------------------------------------------------------------
template <typename WT>
__global__ __launch_bounds__(256) void attn_kernel(const WT* __restrict__ Q,
                                                   const WT* __restrict__ K,
                                                   const WT* __restrict__ V,
                                                   WT* __restrict__ O) {
  __shared__ float Qs[64 * 64];
  __shared__ float Ks[32 * 64];
  __shared__ float Vs[32 * 64];
  __shared__ float Sm[64 * 33];
  __shared__ float m_s[64], l_s[64], a_s[64];

  const int tx = threadIdx.x, ty = threadIdx.y;
  const int tid = ty * 16 + tx;
  const int q0 = blockIdx.x * 64;
  const int h = blockIdx.y, b = blockIdx.z;
  const int base = (b * Hn + h) * Tn * Dn;

#pragma unroll
  for (int it = 0; it < 4; it++) {
    const int e = (tid + it * 256) * 4;
    const int r = e >> 6, d = e & 63;
    float4 q = load4(Q + base + (q0 + r) * Dn + d);
    Qs[r * 64 + d + 0] = q.x;
    Qs[r * 64 + d + 1] = q.y;
    Qs[r * 64 + d + 2] = q.z;
    Qs[r * 64 + d + 3] = q.w;
  }
  if (tid < 64) { m_s[tid] = MASKVAL; l_s[tid] = 0.f; }

  float o[4][4] = {};

  for (int j0 = 0; j0 < q0 + 64; j0 += 32) {
    __syncthreads();  // protect Ks/Vs/Sm (and first-iter Qs/m_s/l_s)
#pragma unroll
    for (int it = 0; it < 2; it++) {
      const int e = (tid + it * 256) * 4;
      const int r = e >> 6, d = e & 63;
      float4 kq = load4(K + base + (j0 + r) * Dn + d);
      Ks[r * 64 + d + 0] = kq.x;
      Ks[r * 64 + d + 1] = kq.y;
      Ks[r * 64 + d + 2] = kq.z;
      Ks[r * 64 + d + 3] = kq.w;
      float4 vq = load4(V + base + (j0 + r) * Dn + d);
      Vs[r * 64 + d + 0] = vq.x;
      Vs[r * 64 + d + 1] = vq.y;
      Vs[r * 64 + d + 2] = vq.z;
      Vs[r * 64 + d + 3] = vq.w;
    }
    __syncthreads();

    // phase 1: S = scale * Q K^T for rows ty*4+i, cols tx*2+jj
    float s0[4] = {}, s1[4] = {};
#pragma unroll 4
    for (int d = 0; d < 64; d += 4) {
      float4 k0v = *(const float4*)(Ks + (tx * 2 + 0) * 64 + d);
      float4 k1v = *(const float4*)(Ks + (tx * 2 + 1) * 64 + d);
#pragma unroll
      for (int i = 0; i < 4; i++) {
        float4 qv = *(const float4*)(Qs + (ty * 4 + i) * 64 + d);
        s0[i] += qv.x * k0v.x + qv.y * k0v.y + qv.z * k0v.z + qv.w * k0v.w;
        s1[i] += qv.x * k1v.x + qv.y * k1v.y + qv.z * k1v.z + qv.w * k1v.w;
      }
    }
#pragma unroll
    for (int i = 0; i < 4; i++) {
      const int r = ty * 4 + i;
      const int c0i = tx * 2;
      float v0 = s0[i] * 0.125f;
      float v1 = s1[i] * 0.125f;
      if (j0 + c0i + 0 > q0 + r) v0 = MASKVAL;
      if (j0 + c0i + 1 > q0 + r) v1 = MASKVAL;
      Sm[r * 33 + c0i + 0] = v0;
      Sm[r * 33 + c0i + 1] = v1;
    }
    __syncthreads();

    // phase 2: online softmax per row (threads 0..63, one row each)
    if (tid < 64) {
      const int r = tid;
      const float mprev = m_s[r];
      float rowmax = MASKVAL;
      for (int c = 0; c < 32; c++) rowmax = fmaxf(rowmax, Sm[r * 33 + c]);
      const float mnew = fmaxf(mprev, rowmax);
      const float alpha = safe_exp(mprev - mnew);
      float sum = 0.f;
      for (int c = 0; c < 32; c++) {
        float p = safe_exp(Sm[r * 33 + c] - mnew);
        Sm[r * 33 + c] = p;
        sum += p;
      }
      l_s[r] = l_s[r] * alpha + sum;
      m_s[r] = mnew;
      a_s[r] = alpha;
    }
    __syncthreads();

    // phase 3: O = O*alpha + P @ V
#pragma unroll
    for (int i = 0; i < 4; i++) {
      const float al = a_s[ty * 4 + i];
      o[i][0] *= al; o[i][1] *= al; o[i][2] *= al; o[i][3] *= al;
    }
#pragma unroll 8
    for (int c = 0; c < 32; c++) {
      float4 v4 = *(const float4*)(Vs + c * 64 + tx * 4);
#pragma unroll
      for (int i = 0; i < 4; i++) {
        const float p = Sm[(ty * 4 + i) * 33 + c];
        o[i][0] += p * v4.x; o[i][1] += p * v4.y;
        o[i][2] += p * v4.z; o[i][3] += p * v4.w;
      }
    }
  }

  // epilogue: write [B,T,C] layout at column h*64 + tx*4 (l >= 1 structurally)
#pragma unroll
  for (int i = 0; i < 4; i++) {
    const int r = ty * 4 + i;
    const float inv = 1.f / l_s[r];
    store4(O + (b * Tn + q0 + r) * Cn + h * 64 + tx * 4,
           o[i][0] * inv, o[i][1] * inv, o[i][2] * inv, o[i][3] * inv);
  }
}

// ---------------------------------------------------------------------------
// Kernel 3: output projection. attn[4096,768](WT) @ Wout[768,768]fp32 -> fp32
// ---------------------------------------------------------------------------
template <typename WT>
__global__ __launch_bounds__(256) void out_gemm(const WT* __restrict__ a,
                                                const float* __restrict__ w,
                                                float* __restrict__ out) {
  __shared__ float As[16 * 68];
  __shared__ float Bs[16 * 68];
  const int tx = threadIdx.x, ty = threadIdx.y;
  const int tid = ty * 16 + tx;
  const int n0 = blockIdx.x * 64;
  const int m0 = blockIdx.y * 64;

  float acc[4][4] = {};

  for (int k0 = 0; k0 < Cn; k0 += 16) {
    __syncthreads();
    {
      const int row = tid >> 2, kkb = (tid & 3) << 2;
      float4 qa = load4(a + (m0 + row) * Cn + k0 + kkb);
      As[(kkb + 0) * 68 + row] = qa.x;
      As[(kkb + 1) * 68 + row] = qa.y;
      As[(kkb + 2) * 68 + row] = qa.z;
      As[(kkb + 3) * 68 + row] = qa.w;
      const int kk = tid >> 4, colb = (tid & 15) << 2;
      float4 qb = *(const float4*)(w + (k0 + kk) * Cn + n0 + colb);
      Bs[kk * 68 + colb + 0] = qb.x;
      Bs[kk * 68 + colb + 1] = qb.y;
      Bs[kk * 68 + colb + 2] = qb.z;
      Bs[kk * 68 + colb + 3] = qb.w;
    }
    __syncthreads();
#pragma unroll
    for (int kk = 0; kk < 16; kk++) {
      float4 a4 = *(const float4*)(As + kk * 68 + ty * 4);
      float4 b4 = *(const float4*)(Bs + kk * 68 + tx * 4);
      float av[4] = {a4.x, a4.y, a4.z, a4.w};
      float bv[4] = {b4.x, b4.y, b4.z, b4.w};
#pragma unroll
      for (int i = 0; i < 4; i++)
#pragma unroll
        for (int j = 0; j < 4; j++) acc[i][j] += av[i] * bv[j];
    }
  }

#pragma unroll
  for (int i = 0; i < 4; i++) {
    const int m = m0 + ty * 4 + i;
    *(float4*)(out + m * Cn + n0 + tx * 4) =
        make_float4(acc[i][0], acc[i][1], acc[i][2], acc[i][3]);
  }
}

// ---------------------------------------------------------------------------
template <typename WT>
static void launch_all(const float* x, const float* Wqkv, const float* Wout,
                       float* out, void* d_ws, hipStream_t stream) {
  const size_t per = (size_t)Bn * Hn * Tn * Dn;  // 3,145,728 elems
  WT* Q    = (WT*)d_ws;                          // [B,H,T,DH]
  WT* K    = Q + per;
  WT* V    = K + per;
  WT* attn = V + per;                            // [B,T,C]
  qkv_gemm<WT><<<dim3(N3n / 64, Mn / 64), dim3(16, 16), 0, stream>>>(x, Wqkv, Q, K, V);
  attn_kernel<WT><<<dim3(Tn / 64, Hn, Bn), dim3(16, 16), 0, stream>>>(Q, K, V, attn);
  out_gemm<WT><<<dim3(Cn / 64, Mn / 64), dim3(16, 16), 0, stream>>>(attn, Wout, out);
}

extern "C" void kernel_launch(void* const* d_in, const int* in_sizes, int n_in,
                              void* d_out, int out_size, void* d_ws, size_t ws_size,
                              hipStream_t stream) {
  const float* x    = (const float*)d_in[0];   // [B,T,C] fp32
  const float* Wqkv = (const float*)d_in[1];   // [C,3C] fp32
  const float* Wout = (const float*)d_in[2];   // [C,C] fp32
  float* out = (float*)d_out;                  // [B,T,C] fp32

  const size_t per = (size_t)Bn * Hn * Tn * Dn;
  // fp32 intermediates need 4 * per * 4 B = 50.3 MB; bf16 fallback 25.2 MB.
  if (ws_size >= 4 * per * sizeof(float)) {
    launch_all<float>(x, Wqkv, Wout, out, d_ws, stream);
  } else {
    launch_all<u16>(x, Wqkv, Wout, out, d_ws, stream);
  }
}

// Round 4
// 434.936 us; speedup vs baseline: 3.1559x; 3.1559x over previous
//
#include <hip/hip_runtime.h>
#include <hip/hip_bf16.h>

// Problem constants (B,T,C,H,DH) = (2,2048,768,12,64)
#define Bn 2
#define Tn 2048
#define Cn 768
#define Hn 12
#define Dn 64
#define N3n 2304
#define Mn 4096   // B*T

#define MASKVAL (-30000.f)   // finite sentinel; scores are O(+-15)

typedef unsigned short u16;
typedef __attribute__((ext_vector_type(8))) unsigned short ushort8_t;
typedef __attribute__((ext_vector_type(8))) short bf16x8;   // 8 bf16 in 4 VGPRs
typedef __attribute__((ext_vector_type(4))) float f32x4;

__device__ __forceinline__ float bf2f(u16 u) {
  union { unsigned int i; float f; } v; v.i = ((unsigned int)u) << 16; return v.f;
}
__device__ __forceinline__ u16 f2bf(float f) {
  union { float f; unsigned int i; } v; v.f = f;
  return (u16)((v.i + 0x7fffu + ((v.i >> 16) & 1u)) >> 16);
}
__device__ __forceinline__ float safe_exp(float x) {
  return __expf(fmaxf(x, -80.f));   // arg in [-80,0]; never inf/NaN
}
__device__ __forceinline__ float4 load4(const u16* p) {
  ushort4 q = *(const ushort4*)p;
  return make_float4(bf2f(q.x), bf2f(q.y), bf2f(q.z), bf2f(q.w));
}

// ---------------------------------------------------------------------------
// Kernel 1: QKV projection (fp32 math, scalar VALU — MFMA next round).
// x[4096,768]fp32 @ Wqkv[768,2304]fp32 -> Q,K bf16 [B,H,T,DH], V bf16 [B,H,DH,T]
// ---------------------------------------------------------------------------
__global__ __launch_bounds__(256) void qkv_gemm(const float* __restrict__ x,
                                                const float* __restrict__ w,
                                                u16* __restrict__ Q,
                                                u16* __restrict__ K,
                                                u16* __restrict__ VT) {
  __shared__ float As[16 * 68];  // [kk][row]
  __shared__ float Bs[16 * 68];  // [kk][col]
  const int tx = threadIdx.x, ty = threadIdx.y;
  const int tid = ty * 16 + tx;
  const int n0 = blockIdx.x * 64;
  const int m0 = blockIdx.y * 64;

  float acc[4][4] = {};

  for (int k0 = 0; k0 < Cn; k0 += 16) {
    __syncthreads();
    {
      const int row = tid >> 2, kkb = (tid & 3) << 2;
      float4 qa = *(const float4*)(x + (m0 + row) * Cn + k0 + kkb);
      As[(kkb + 0) * 68 + row] = qa.x;
      As[(kkb + 1) * 68 + row] = qa.y;
      As[(kkb + 2) * 68 + row] = qa.z;
      As[(kkb + 3) * 68 + row] = qa.w;
      const int kk = tid >> 4, colb = (tid & 15) << 2;
      float4 qb = *(const float4*)(w + (k0 + kk) * N3n + n0 + colb);
      Bs[kk * 68 + colb + 0] = qb.x;
      Bs[kk * 68 + colb + 1] = qb.y;
      Bs[kk * 68 + colb + 2] = qb.z;
      Bs[kk * 68 + colb + 3] = qb.w;
    }
    __syncthreads();
#pragma unroll
    for (int kk = 0; kk < 16; kk++) {
      float4 a4 = *(const float4*)(As + kk * 68 + ty * 4);
      float4 b4 = *(const float4*)(Bs + kk * 68 + tx * 4);
      float a[4] = {a4.x, a4.y, a4.z, a4.w};
      float b[4] = {b4.x, b4.y, b4.z, b4.w};
#pragma unroll
      for (int i = 0; i < 4; i++)
#pragma unroll
        for (int j = 0; j < 4; j++) acc[i][j] += a[i] * b[j];
    }
  }

  const int which = n0 / Cn;          // 0=Q 1=K 2=V, uniform per block
  const int c0 = n0 - which * Cn;
  const int h = c0 >> 6;              // uniform per block
  if (which < 2) {
    u16* dst = (which == 0) ? Q : K;
#pragma unroll
    for (int i = 0; i < 4; i++) {
      const int m = m0 + ty * 4 + i;
      const int b = m >> 11, t = m & (Tn - 1);
      ushort4 st;
      st.x = f2bf(acc[i][0]); st.y = f2bf(acc[i][1]);
      st.z = f2bf(acc[i][2]); st.w = f2bf(acc[i][3]);
      *(ushort4*)(dst + (((b * Hn + h) * Tn + t) * Dn) + tx * 4) = st;
    }
  } else {
    // V transposed: VT[b][h][d][t], d = tx*4+j, t = m. Scalar stores; L2 merges.
#pragma unroll
    for (int i = 0; i < 4; i++) {
      const int m = m0 + ty * 4 + i;
      const int b = m >> 11, t = m & (Tn - 1);
      u16* vb = VT + ((size_t)(b * Hn + h) * Dn) * Tn + t;
#pragma unroll
      for (int j = 0; j < 4; j++) vb[(size_t)(tx * 4 + j) * Tn] = f2bf(acc[i][j]);
    }
  }
}

// ---------------------------------------------------------------------------
// Kernel 2: causal flash attention on MFMA (bf16 in, fp32 acc). Inf-free.
// Block = 4 waves, 64 q-rows (16/wave), Bc=64. One block per (q-tile, h, b).
// Layouts (m89/m120-verified): A: m=lane&15, k=(lane>>4)*8+j.
//                              B: n=lane&15, k=(lane>>4)*8+j.
//                              C/D: col=lane&15, row=(lane>>4)*4+reg.
// ---------------------------------------------------------------------------
#define KP 72   // LDS row pitch in u16 (144 B: 16B-aligned, banks spread)

__global__ __launch_bounds__(256) void attn_kernel(const u16* __restrict__ Q,
                                                   const u16* __restrict__ K,
                                                   const u16* __restrict__ VT,
                                                   u16* __restrict__ O) {
  __shared__ u16 Ks[64 * KP];        // K-tile  [kv_row][d]
  __shared__ u16 Vt[64 * KP];        // V-tile  [d][kv_row]
  __shared__ u16 Pw[4][16 * KP];     // per-wave P round-trip [q_row][kv_row]

  const int tid = threadIdx.x;
  const int wv = tid >> 6, lane = tid & 63;
  const int lo = lane & 15, quad = lane >> 4;
  const int q0 = blockIdx.x * 64;
  const int h = blockIdx.y, b = blockIdx.z;
  const size_t base = (size_t)(b * Hn + h) * Tn * Dn;   // Q/K [.,T,64]
  const size_t vtb  = (size_t)(b * Hn + h) * Dn * Tn;   // VT  [.,64,T]

  // Q A-fragments straight from global (once)
  const u16* qp = Q + base + (size_t)(q0 + (wv << 4) + lo) * Dn + (quad << 3);
  const bf16x8 aq0 = *(const bf16x8*)qp;
  const bf16x8 aq1 = *(const bf16x8*)(qp + 32);

  f32x4 o[4] = {f32x4{0,0,0,0}, f32x4{0,0,0,0}, f32x4{0,0,0,0}, f32x4{0,0,0,0}};
  float m4[4] = {MASKVAL, MASKVAL, MASKVAL, MASKVAL};
  float l4[4] = {0.f, 0.f, 0.f, 0.f};

  for (int j0 = 0; j0 <= q0; j0 += 64) {
    __syncthreads();   // protect Ks/Vt against previous iteration's readers
    // stage K rows [j0..j0+63][0..63] and VT rows [0..63][j0..j0+63]
    for (int c = tid; c < 512; c += 256) {
      const int r = c >> 3, cc = (c & 7) << 3;
      *(ushort8_t*)(&Ks[r * KP + cc]) =
          *(const ushort8_t*)(K + base + (size_t)(j0 + r) * Dn + cc);
      *(ushort8_t*)(&Vt[r * KP + cc]) =
          *(const ushort8_t*)(VT + vtb + (size_t)r * Tn + j0 + cc);
    }
    __syncthreads();

    // ---- S = Q K^T (scale 1/8), C-layout: row=quad*4+reg, col=nt*16+lo ----
    f32x4 s[4];
#pragma unroll
    for (int nt = 0; nt < 4; nt++) {
      const bf16x8 bk0 = *(const bf16x8*)(&Ks[(nt * 16 + lo) * KP + (quad << 3)]);
      const bf16x8 bk1 = *(const bf16x8*)(&Ks[(nt * 16 + lo) * KP + 32 + (quad << 3)]);
      f32x4 acc = {0.f, 0.f, 0.f, 0.f};
      acc = __builtin_amdgcn_mfma_f32_16x16x32_bf16(aq0, bk0, acc, 0, 0, 0);
      acc = __builtin_amdgcn_mfma_f32_16x16x32_bf16(aq1, bk1, acc, 0, 0, 0);
      s[nt] = acc;
    }

    // scale + causal mask (only the diagonal tile straddles: j0 == q0)
    if (j0 == q0) {
#pragma unroll
      for (int nt = 0; nt < 4; nt++)
#pragma unroll
        for (int r = 0; r < 4; r++) {
          const int row = (wv << 4) + (quad << 2) + r;   // local q row 0..63
          const int col = nt * 16 + lo;                  // local kv col 0..63
          s[nt][r] = (col > row) ? MASKVAL : s[nt][r] * 0.125f;
        }
    } else {
#pragma unroll
      for (int nt = 0; nt < 4; nt++)
#pragma unroll
        for (int r = 0; r < 4; r++) s[nt][r] *= 0.125f;
    }

    // ---- online softmax, stats in registers, 16-lane butterflies ----
    float alpha[4], psum[4];
#pragma unroll
    for (int r = 0; r < 4; r++) {
      float mx = fmaxf(fmaxf(s[0][r], s[1][r]), fmaxf(s[2][r], s[3][r]));
#pragma unroll
      for (int off = 1; off < 16; off <<= 1) mx = fmaxf(mx, __shfl_xor(mx, off));
      const float mnew = fmaxf(m4[r], mx);
      alpha[r] = safe_exp(m4[r] - mnew);
      m4[r] = mnew;
      float sum = 0.f;
#pragma unroll
      for (int nt = 0; nt < 4; nt++) {
        const float p = safe_exp(s[nt][r] - mnew);
        s[nt][r] = p;
        sum += p;
      }
#pragma unroll
      for (int off = 1; off < 16; off <<= 1) sum += __shfl_xor(sum, off);
      psum[r] = sum;
      l4[r] = l4[r] * alpha[r] + sum;
    }

    // ---- P: C-layout -> LDS -> A-layout (per-wave, no barrier needed) ----
    u16* pw = Pw[wv];
#pragma unroll
    for (int nt = 0; nt < 4; nt++)
#pragma unroll
      for (int r = 0; r < 4; r++)
        pw[((quad << 2) + r) * KP + nt * 16 + lo] = f2bf(s[nt][r]);
    const bf16x8 pa0 = *(const bf16x8*)(&pw[lo * KP + (quad << 3)]);
    const bf16x8 pa1 = *(const bf16x8*)(&pw[lo * KP + 32 + (quad << 3)]);

    // ---- O = O*alpha + P V ----
#pragma unroll
    for (int nt = 0; nt < 4; nt++) {
#pragma unroll
      for (int r = 0; r < 4; r++) o[nt][r] *= alpha[r];
      const bf16x8 bv0 = *(const bf16x8*)(&Vt[(nt * 16 + lo) * KP + (quad << 3)]);
      const bf16x8 bv1 = *(const bf16x8*)(&Vt[(nt * 16 + lo) * KP + 32 + (quad << 3)]);
      o[nt] = __builtin_amdgcn_mfma_f32_16x16x32_bf16(pa0, bv0, o[nt], 0, 0, 0);
      o[nt] = __builtin_amdgcn_mfma_f32_16x16x32_bf16(pa1, bv1, o[nt], 0, 0, 0);
    }
  }

  // epilogue: normalize and write attn [B,T,C] at col h*64 (l>=1 structurally)
  float inv[4];
#pragma unroll
  for (int r = 0; r < 4; r++) inv[r] = 1.f / l4[r];
#pragma unroll
  for (int nt = 0; nt < 4; nt++)
#pragma unroll
    for (int r = 0; r < 4; r++) {
      const int row = q0 + (wv << 4) + (quad << 2) + r;
      const int col = h * 64 + nt * 16 + lo;
      O[(size_t)(b * Tn + row) * Cn + col] = f2bf(o[nt][r] * inv[r]);
    }
}

// ---------------------------------------------------------------------------
// Kernel 3: output projection. attn[4096,768]bf16 @ Wout[768,768]fp32 -> fp32
// ---------------------------------------------------------------------------
__global__ __launch_bounds__(256) void out_gemm(const u16* __restrict__ a,
                                                const float* __restrict__ w,
                                                float* __restrict__ out) {
  __shared__ float As[16 * 68];
  __shared__ float Bs[16 * 68];
  const int tx = threadIdx.x, ty = threadIdx.y;
  const int tid = ty * 16 + tx;
  const int n0 = blockIdx.x * 64;
  const int m0 = blockIdx.y * 64;

  float acc[4][4] = {};

  for (int k0 = 0; k0 < Cn; k0 += 16) {
    __syncthreads();
    {
      const int row = tid >> 2, kkb = (tid & 3) << 2;
      float4 qa = load4(a + (m0 + row) * Cn + k0 + kkb);
      As[(kkb + 0) * 68 + row] = qa.x;
      As[(kkb + 1) * 68 + row] = qa.y;
      As[(kkb + 2) * 68 + row] = qa.z;
      As[(kkb + 3) * 68 + row] = qa.w;
      const int kk = tid >> 4, colb = (tid & 15) << 2;
      float4 qb = *(const float4*)(w + (k0 + kk) * Cn + n0 + colb);
      Bs[kk * 68 + colb + 0] = qb.x;
      Bs[kk * 68 + colb + 1] = qb.y;
      Bs[kk * 68 + colb + 2] = qb.z;
      Bs[kk * 68 + colb + 3] = qb.w;
    }
    __syncthreads();
#pragma unroll
    for (int kk = 0; kk < 16; kk++) {
      float4 a4 = *(const float4*)(As + kk * 68 + ty * 4);
      float4 b4 = *(const float4*)(Bs + kk * 68 + tx * 4);
      float av[4] = {a4.x, a4.y, a4.z, a4.w};
      float bv[4] = {b4.x, b4.y, b4.z, b4.w};
#pragma unroll
      for (int i = 0; i < 4; i++)
#pragma unroll
        for (int j = 0; j < 4; j++) acc[i][j] += av[i] * bv[j];
    }
  }

#pragma unroll
  for (int i = 0; i < 4; i++) {
    const int m = m0 + ty * 4 + i;
    *(float4*)(out + m * Cn + n0 + tx * 4) =
        make_float4(acc[i][0], acc[i][1], acc[i][2], acc[i][3]);
  }
}

// ---------------------------------------------------------------------------
extern "C" void kernel_launch(void* const* d_in, const int* in_sizes, int n_in,
                              void* d_out, int out_size, void* d_ws, size_t ws_size,
                              hipStream_t stream) {
  const float* x    = (const float*)d_in[0];   // [B,T,C] fp32
  const float* Wqkv = (const float*)d_in[1];   // [C,3C] fp32
  const float* Wout = (const float*)d_in[2];   // [C,C] fp32
  float* out = (float*)d_out;                  // [B,T,C] fp32

  const size_t per = (size_t)Bn * Hn * Tn * Dn;  // 3,145,728 elems
  u16* Q    = (u16*)d_ws;                        // [B,H,T,DH]  bf16
  u16* K    = Q + per;                           // [B,H,T,DH]  bf16
  u16* VT   = K + per;                           // [B,H,DH,T]  bf16
  u16* attn = VT + per;                          // [B,T,C]     bf16
  // total ws use: 4 * per * 2 B = 25.2 MB

  qkv_gemm<<<dim3(N3n / 64, Mn / 64), dim3(16, 16), 0, stream>>>(x, Wqkv, Q, K, VT);
  attn_kernel<<<dim3(Tn / 64, Hn, Bn), dim3(256), 0, stream>>>(Q, K, VT, attn);
  out_gemm<<<dim3(Cn / 64, Mn / 64), dim3(16, 16), 0, stream>>>(attn, Wout, out);
}

// Round 5
// 232.214 us; speedup vs baseline: 5.9111x; 1.8730x over previous
//
#include <hip/hip_runtime.h>
#include <hip/hip_bf16.h>

// Problem constants (B,T,C,H,DH) = (2,2048,768,12,64)
#define Bn 2
#define Tn 2048
#define Cn 768
#define Hn 12
#define Dn 64
#define N3n 2304
#define Mn 4096   // B*T

#define MASKVAL (-30000.f)   // finite sentinel; scores are O(+-15)

typedef unsigned short u16;
typedef __attribute__((ext_vector_type(8))) unsigned short ushort8_t;
typedef __attribute__((ext_vector_type(8))) short bf16x8;   // 8 bf16 in 4 VGPRs
typedef __attribute__((ext_vector_type(4))) float f32x4;

__device__ __forceinline__ float bf2f(u16 u) {
  union { unsigned int i; float f; } v; v.i = ((unsigned int)u) << 16; return v.f;
}
__device__ __forceinline__ u16 f2bf(float f) {
  union { float f; unsigned int i; } v; v.f = f;
  return (u16)((v.i + 0x7fffu + ((v.i >> 16) & 1u)) >> 16);
}
__device__ __forceinline__ float safe_exp(float x) {
  return __expf(fmaxf(x, -80.f));   // arg in [-80,0]; never inf/NaN
}

// ---------------------------------------------------------------------------
// Prep 1: elementwise fp32 -> bf16 cast (x). n must be a multiple of 1024.
// ---------------------------------------------------------------------------
__global__ __launch_bounds__(256) void cast_bf16(const float* __restrict__ in,
                                                 u16* __restrict__ out) {
  const int i = (blockIdx.x * 256 + threadIdx.x) * 4;
  float4 v = *(const float4*)(in + i);
  ushort4 s;
  s.x = f2bf(v.x); s.y = f2bf(v.y); s.z = f2bf(v.z); s.w = f2bf(v.w);
  *(ushort4*)(out + i) = s;
}

// ---------------------------------------------------------------------------
// Prep 2: transpose-cast. in fp32 [R][Cc] -> out bf16 [Cc][R]. 32x32 LDS tile.
// Block (32,8); R, Cc multiples of 32.
// ---------------------------------------------------------------------------
__global__ __launch_bounds__(256) void transpose_cast(const float* __restrict__ in,
                                                      u16* __restrict__ out,
                                                      int R, int Cc) {
  __shared__ u16 t[32][33];
  const int c0 = blockIdx.x * 32, r0 = blockIdx.y * 32;
  const int tx = threadIdx.x, ty = threadIdx.y;
#pragma unroll
  for (int i = 0; i < 4; i++)
    t[ty * 4 + i][tx] = f2bf(in[(size_t)(r0 + ty * 4 + i) * Cc + c0 + tx]);
  __syncthreads();
#pragma unroll
  for (int i = 0; i < 4; i++)
    out[(size_t)(c0 + ty * 4 + i) * R + r0 + tx] = t[tx][ty * 4 + i];
}

// ---------------------------------------------------------------------------
// MFMA GEMM: D[M=128/blk][N=128/blk] = A[M][768] @ BT[N][768]^T, bf16 in,
// fp32 acc. 4 waves in 2x2 quadrants, 4x4 subtiles of 16x16x32 per wave.
// LDS pitch 40 u16 (80 B): b128 frag reads 16B-aligned, 2-way banks (free).
// EPI 0: scatter to Q,K [B,H,T,DH] / VT [B,H,DH,T] bf16.  EPI 1: fp32 out.
// ---------------------------------------------------------------------------
#define GP 40

template <int EPI>
__global__ __launch_bounds__(256) void mfma_gemm(const u16* __restrict__ A,
                                                 const u16* __restrict__ BT,
                                                 u16* __restrict__ Q,
                                                 u16* __restrict__ Kd,
                                                 u16* __restrict__ VT,
                                                 float* __restrict__ out) {
  __shared__ __align__(16) u16 Ash[128 * GP];
  __shared__ __align__(16) u16 Bsh[128 * GP];
  const int tid = threadIdx.x;
  const int wv = tid >> 6, lane = tid & 63;
  const int lo = lane & 15, quad = lane >> 4;
  const int wm = wv & 1, wn = wv >> 1;
  const int n0 = blockIdx.x * 128;
  const int m0 = blockIdx.y * 128;

  f32x4 acc[4][4];
#pragma unroll
  for (int i = 0; i < 4; i++)
#pragma unroll
    for (int j = 0; j < 4; j++) acc[i][j] = f32x4{0.f, 0.f, 0.f, 0.f};

  for (int k0 = 0; k0 < Cn; k0 += 32) {
    __syncthreads();
    // stage A-tile [128][32] and B-tile [128][32] (both [row][k], pitch GP)
#pragma unroll
    for (int it = 0; it < 2; it++) {
      const int c = tid + it * 256;           // 0..511 chunk of 8
      const int row = c >> 2, col = (c & 3) << 3;
      *(ushort8_t*)&Ash[row * GP + col] =
          *(const ushort8_t*)(A + (size_t)(m0 + row) * Cn + k0 + col);
      *(ushort8_t*)&Bsh[row * GP + col] =
          *(const ushort8_t*)(BT + (size_t)(n0 + row) * Cn + k0 + col);
    }
    __syncthreads();

    bf16x8 af[4], bfr[4];
#pragma unroll
    for (int t = 0; t < 4; t++) {
      af[t]  = *(const bf16x8*)&Ash[(wm * 64 + t * 16 + lo) * GP + (quad << 3)];
      bfr[t] = *(const bf16x8*)&Bsh[(wn * 64 + t * 16 + lo) * GP + (quad << 3)];
    }
#pragma unroll
    for (int mt = 0; mt < 4; mt++)
#pragma unroll
      for (int nt = 0; nt < 4; nt++)
        acc[mt][nt] = __builtin_amdgcn_mfma_f32_16x16x32_bf16(af[mt], bfr[nt],
                                                              acc[mt][nt], 0, 0, 0);
  }

  // ---- epilogue. C/D layout: col = lo, row = quad*4 + r (m89-verified) ----
  if (EPI == 0) {
    const int which = n0 / Cn;                 // 0=Q 1=K 2=V, uniform per block
    const int h = ((n0 % Cn) >> 6) + wn;       // uniform per wave
    const int bb = m0 >> 11;                   // uniform per block (128 | 2048)
    const int t_base = (m0 & (Tn - 1)) + wm * 64;
    if (which < 2) {
      u16* dst = ((which == 0) ? Q : Kd) + (size_t)(bb * Hn + h) * Tn * Dn;
#pragma unroll
      for (int mt = 0; mt < 4; mt++)
#pragma unroll
        for (int nt = 0; nt < 4; nt++)
#pragma unroll
          for (int r = 0; r < 4; r++) {
            const int t = t_base + mt * 16 + (quad << 2) + r;
            dst[(size_t)t * Dn + nt * 16 + lo] = f2bf(acc[mt][nt][r]);
          }
    } else {
      u16* dst = VT + (size_t)(bb * Hn + h) * Dn * Tn;
#pragma unroll
      for (int mt = 0; mt < 4; mt++)
#pragma unroll
        for (int nt = 0; nt < 4; nt++) {
          const int t = t_base + mt * 16 + (quad << 2);
          const int d = nt * 16 + lo;
          ushort4 st;
          st.x = f2bf(acc[mt][nt][0]); st.y = f2bf(acc[mt][nt][1]);
          st.z = f2bf(acc[mt][nt][2]); st.w = f2bf(acc[mt][nt][3]);
          *(ushort4*)&dst[(size_t)d * Tn + t] = st;
        }
    }
  } else {
#pragma unroll
    for (int mt = 0; mt < 4; mt++)
#pragma unroll
      for (int nt = 0; nt < 4; nt++)
#pragma unroll
        for (int r = 0; r < 4; r++) {
          const int m = m0 + wm * 64 + mt * 16 + (quad << 2) + r;
          out[(size_t)m * Cn + n0 + wn * 64 + nt * 16 + lo] = acc[mt][nt][r];
        }
  }
}

// ---------------------------------------------------------------------------
// Causal flash attention on MFMA (unchanged from R4 — verified).
// ---------------------------------------------------------------------------
#define KP 72   // LDS row pitch in u16 (144 B: 16B-aligned)

__global__ __launch_bounds__(256) void attn_kernel(const u16* __restrict__ Q,
                                                   const u16* __restrict__ K,
                                                   const u16* __restrict__ VT,
                                                   u16* __restrict__ O) {
  __shared__ u16 Ks[64 * KP];        // K-tile  [kv_row][d]
  __shared__ u16 Vt[64 * KP];        // V-tile  [d][kv_row]
  __shared__ u16 Pw[4][16 * KP];     // per-wave P round-trip [q_row][kv_row]

  const int tid = threadIdx.x;
  const int wv = tid >> 6, lane = tid & 63;
  const int lo = lane & 15, quad = lane >> 4;
  const int q0 = blockIdx.x * 64;
  const int h = blockIdx.y, b = blockIdx.z;
  const size_t base = (size_t)(b * Hn + h) * Tn * Dn;   // Q/K [.,T,64]
  const size_t vtb  = (size_t)(b * Hn + h) * Dn * Tn;   // VT  [.,64,T]

  const u16* qp = Q + base + (size_t)(q0 + (wv << 4) + lo) * Dn + (quad << 3);
  const bf16x8 aq0 = *(const bf16x8*)qp;
  const bf16x8 aq1 = *(const bf16x8*)(qp + 32);

  f32x4 o[4] = {f32x4{0,0,0,0}, f32x4{0,0,0,0}, f32x4{0,0,0,0}, f32x4{0,0,0,0}};
  float m4[4] = {MASKVAL, MASKVAL, MASKVAL, MASKVAL};
  float l4[4] = {0.f, 0.f, 0.f, 0.f};

  for (int j0 = 0; j0 <= q0; j0 += 64) {
    __syncthreads();
    for (int c = tid; c < 512; c += 256) {
      const int r = c >> 3, cc = (c & 7) << 3;
      *(ushort8_t*)(&Ks[r * KP + cc]) =
          *(const ushort8_t*)(K + base + (size_t)(j0 + r) * Dn + cc);
      *(ushort8_t*)(&Vt[r * KP + cc]) =
          *(const ushort8_t*)(VT + vtb + (size_t)r * Tn + j0 + cc);
    }
    __syncthreads();

    f32x4 s[4];
#pragma unroll
    for (int nt = 0; nt < 4; nt++) {
      const bf16x8 bk0 = *(const bf16x8*)(&Ks[(nt * 16 + lo) * KP + (quad << 3)]);
      const bf16x8 bk1 = *(const bf16x8*)(&Ks[(nt * 16 + lo) * KP + 32 + (quad << 3)]);
      f32x4 a = {0.f, 0.f, 0.f, 0.f};
      a = __builtin_amdgcn_mfma_f32_16x16x32_bf16(aq0, bk0, a, 0, 0, 0);
      a = __builtin_amdgcn_mfma_f32_16x16x32_bf16(aq1, bk1, a, 0, 0, 0);
      s[nt] = a;
    }

    if (j0 == q0) {
#pragma unroll
      for (int nt = 0; nt < 4; nt++)
#pragma unroll
        for (int r = 0; r < 4; r++) {
          const int row = (wv << 4) + (quad << 2) + r;
          const int col = nt * 16 + lo;
          s[nt][r] = (col > row) ? MASKVAL : s[nt][r] * 0.125f;
        }
    } else {
#pragma unroll
      for (int nt = 0; nt < 4; nt++)
#pragma unroll
        for (int r = 0; r < 4; r++) s[nt][r] *= 0.125f;
    }

    float alpha[4];
#pragma unroll
    for (int r = 0; r < 4; r++) {
      float mx = fmaxf(fmaxf(s[0][r], s[1][r]), fmaxf(s[2][r], s[3][r]));
#pragma unroll
      for (int off = 1; off < 16; off <<= 1) mx = fmaxf(mx, __shfl_xor(mx, off));
      const float mnew = fmaxf(m4[r], mx);
      alpha[r] = safe_exp(m4[r] - mnew);
      m4[r] = mnew;
      float sum = 0.f;
#pragma unroll
      for (int nt = 0; nt < 4; nt++) {
        const float p = safe_exp(s[nt][r] - mnew);
        s[nt][r] = p;
        sum += p;
      }
#pragma unroll
      for (int off = 1; off < 16; off <<= 1) sum += __shfl_xor(sum, off);
      l4[r] = l4[r] * alpha[r] + sum;
    }

    u16* pw = Pw[wv];
#pragma unroll
    for (int nt = 0; nt < 4; nt++)
#pragma unroll
      for (int r = 0; r < 4; r++)
        pw[((quad << 2) + r) * KP + nt * 16 + lo] = f2bf(s[nt][r]);
    const bf16x8 pa0 = *(const bf16x8*)(&pw[lo * KP + (quad << 3)]);
    const bf16x8 pa1 = *(const bf16x8*)(&pw[lo * KP + 32 + (quad << 3)]);

#pragma unroll
    for (int nt = 0; nt < 4; nt++) {
#pragma unroll
      for (int r = 0; r < 4; r++) o[nt][r] *= alpha[r];
      const bf16x8 bv0 = *(const bf16x8*)(&Vt[(nt * 16 + lo) * KP + (quad << 3)]);
      const bf16x8 bv1 = *(const bf16x8*)(&Vt[(nt * 16 + lo) * KP + 32 + (quad << 3)]);
      o[nt] = __builtin_amdgcn_mfma_f32_16x16x32_bf16(pa0, bv0, o[nt], 0, 0, 0);
      o[nt] = __builtin_amdgcn_mfma_f32_16x16x32_bf16(pa1, bv1, o[nt], 0, 0, 0);
    }
  }

  float inv[4];
#pragma unroll
  for (int r = 0; r < 4; r++) inv[r] = 1.f / l4[r];
#pragma unroll
  for (int nt = 0; nt < 4; nt++)
#pragma unroll
    for (int r = 0; r < 4; r++) {
      const int row = q0 + (wv << 4) + (quad << 2) + r;
      const int col = h * 64 + nt * 16 + lo;
      O[(size_t)(b * Tn + row) * Cn + col] = f2bf(o[nt][r] * inv[r]);
    }
}

// ---------------------------------------------------------------------------
extern "C" void kernel_launch(void* const* d_in, const int* in_sizes, int n_in,
                              void* d_out, int out_size, void* d_ws, size_t ws_size,
                              hipStream_t stream) {
  const float* x    = (const float*)d_in[0];   // [B,T,C] fp32
  const float* Wqkv = (const float*)d_in[1];   // [C,3C] fp32
  const float* Wout = (const float*)d_in[2];   // [C,C] fp32
  float* out = (float*)d_out;                  // [B,T,C] fp32

  const size_t per = (size_t)Bn * Hn * Tn * Dn;     // 3,145,728 elems
  u16* xb    = (u16*)d_ws;                          // [4096,768] bf16
  u16* WqkvT = xb + (size_t)Mn * Cn;                // [2304,768] bf16
  u16* WoutT = WqkvT + (size_t)N3n * Cn;            // [768,768]  bf16
  u16* Qb    = WoutT + (size_t)Cn * Cn;             // [B,H,T,DH] bf16
  u16* Kb    = Qb + per;                            // [B,H,T,DH] bf16
  u16* VTb   = Kb + per;                            // [B,H,DH,T] bf16
  u16* attn  = VTb + per;                           // [B,T,C]    bf16
  // total ws use: 18.1M u16 = 36.2 MB (< 50.3 MB available)

  cast_bf16<<<(Mn * Cn) / 1024, 256, 0, stream>>>(x, xb);
  transpose_cast<<<dim3(N3n / 32, Cn / 32), dim3(32, 8), 0, stream>>>(Wqkv, WqkvT, Cn, N3n);
  transpose_cast<<<dim3(Cn / 32, Cn / 32), dim3(32, 8), 0, stream>>>(Wout, WoutT, Cn, Cn);

  mfma_gemm<0><<<dim3(N3n / 128, Mn / 128), 256, 0, stream>>>(xb, WqkvT, Qb, Kb, VTb, nullptr);
  attn_kernel<<<dim3(Tn / 64, Hn, Bn), 256, 0, stream>>>(Qb, Kb, VTb, attn);
  mfma_gemm<1><<<dim3(Cn / 128, Mn / 128), 256, 0, stream>>>(attn, WoutT, nullptr, nullptr, nullptr, out);
}

// Round 6
// 212.853 us; speedup vs baseline: 6.4488x; 1.0910x over previous
//
#include <hip/hip_runtime.h>
#include <hip/hip_bf16.h>

// Problem constants (B,T,C,H,DH) = (2,2048,768,12,64)
#define Bn 2
#define Tn 2048
#define Cn 768
#define Hn 12
#define Dn 64
#define N3n 2304
#define Mn 4096   // B*T

#define MASKVAL (-30000.f)   // finite sentinel; scores are O(+-15)
#define NITEMS 768           // 32 q-tiles * 12 heads * 2 batch

typedef unsigned short u16;
typedef __attribute__((ext_vector_type(8))) unsigned short ushort8_t;
typedef __attribute__((ext_vector_type(8))) short bf16x8;   // 8 bf16 in 4 VGPRs
typedef __attribute__((ext_vector_type(4))) float f32x4;

__device__ __forceinline__ float bf2f(u16 u) {
  union { unsigned int i; float f; } v; v.i = ((unsigned int)u) << 16; return v.f;
}
__device__ __forceinline__ u16 f2bf(float f) {
  union { float f; unsigned int i; } v; v.f = f;
  return (u16)((v.i + 0x7fffu + ((v.i >> 16) & 1u)) >> 16);
}
__device__ __forceinline__ float safe_exp(float x) {
  return __expf(fmaxf(x, -80.f));   // arg in [-80,0]; never inf/NaN
}

// ---------------------------------------------------------------------------
// Prep 1: elementwise fp32 -> bf16 cast (x). Also zeroes the attn work counter
// (block 0, thread 0) — runs before attn in stream order, so no extra dispatch.
// ---------------------------------------------------------------------------
__global__ __launch_bounds__(256) void cast_bf16(const float* __restrict__ in,
                                                 u16* __restrict__ out,
                                                 int* __restrict__ counter) {
  if (blockIdx.x == 0 && threadIdx.x == 0) *counter = 0;
  const int i = (blockIdx.x * 256 + threadIdx.x) * 4;
  float4 v = *(const float4*)(in + i);
  ushort4 s;
  s.x = f2bf(v.x); s.y = f2bf(v.y); s.z = f2bf(v.z); s.w = f2bf(v.w);
  *(ushort4*)(out + i) = s;
}

// ---------------------------------------------------------------------------
// Prep 2: transpose-cast. in fp32 [R][Cc] -> out bf16 [Cc][R]. 32x32 LDS tile.
// ---------------------------------------------------------------------------
__global__ __launch_bounds__(256) void transpose_cast(const float* __restrict__ in,
                                                      u16* __restrict__ out,
                                                      int R, int Cc) {
  __shared__ u16 t[32][33];
  const int c0 = blockIdx.x * 32, r0 = blockIdx.y * 32;
  const int tx = threadIdx.x, ty = threadIdx.y;
#pragma unroll
  for (int i = 0; i < 4; i++)
    t[ty * 4 + i][tx] = f2bf(in[(size_t)(r0 + ty * 4 + i) * Cc + c0 + tx]);
  __syncthreads();
#pragma unroll
  for (int i = 0; i < 4; i++)
    out[(size_t)(c0 + ty * 4 + i) * R + r0 + tx] = t[tx][ty * 4 + i];
}

// ---------------------------------------------------------------------------
// MFMA GEMM (unchanged from R5 — verified). 128x128 tile, BK=32, 4 waves.
// ---------------------------------------------------------------------------
#define GP 40

template <int EPI>
__global__ __launch_bounds__(256) void mfma_gemm(const u16* __restrict__ A,
                                                 const u16* __restrict__ BT,
                                                 u16* __restrict__ Q,
                                                 u16* __restrict__ Kd,
                                                 u16* __restrict__ VT,
                                                 float* __restrict__ out) {
  __shared__ __align__(16) u16 Ash[128 * GP];
  __shared__ __align__(16) u16 Bsh[128 * GP];
  const int tid = threadIdx.x;
  const int wv = tid >> 6, lane = tid & 63;
  const int lo = lane & 15, quad = lane >> 4;
  const int wm = wv & 1, wn = wv >> 1;
  const int n0 = blockIdx.x * 128;
  const int m0 = blockIdx.y * 128;

  f32x4 acc[4][4];
#pragma unroll
  for (int i = 0; i < 4; i++)
#pragma unroll
    for (int j = 0; j < 4; j++) acc[i][j] = f32x4{0.f, 0.f, 0.f, 0.f};

  for (int k0 = 0; k0 < Cn; k0 += 32) {
    __syncthreads();
#pragma unroll
    for (int it = 0; it < 2; it++) {
      const int c = tid + it * 256;
      const int row = c >> 2, col = (c & 3) << 3;
      *(ushort8_t*)&Ash[row * GP + col] =
          *(const ushort8_t*)(A + (size_t)(m0 + row) * Cn + k0 + col);
      *(ushort8_t*)&Bsh[row * GP + col] =
          *(const ushort8_t*)(BT + (size_t)(n0 + row) * Cn + k0 + col);
    }
    __syncthreads();

    bf16x8 af[4], bfr[4];
#pragma unroll
    for (int t = 0; t < 4; t++) {
      af[t]  = *(const bf16x8*)&Ash[(wm * 64 + t * 16 + lo) * GP + (quad << 3)];
      bfr[t] = *(const bf16x8*)&Bsh[(wn * 64 + t * 16 + lo) * GP + (quad << 3)];
    }
#pragma unroll
    for (int mt = 0; mt < 4; mt++)
#pragma unroll
      for (int nt = 0; nt < 4; nt++)
        acc[mt][nt] = __builtin_amdgcn_mfma_f32_16x16x32_bf16(af[mt], bfr[nt],
                                                              acc[mt][nt], 0, 0, 0);
  }

  if (EPI == 0) {
    const int which = n0 / Cn;
    const int h = ((n0 % Cn) >> 6) + wn;
    const int bb = m0 >> 11;
    const int t_base = (m0 & (Tn - 1)) + wm * 64;
    if (which < 2) {
      u16* dst = ((which == 0) ? Q : Kd) + (size_t)(bb * Hn + h) * Tn * Dn;
#pragma unroll
      for (int mt = 0; mt < 4; mt++)
#pragma unroll
        for (int nt = 0; nt < 4; nt++)
#pragma unroll
          for (int r = 0; r < 4; r++) {
            const int t = t_base + mt * 16 + (quad << 2) + r;
            dst[(size_t)t * Dn + nt * 16 + lo] = f2bf(acc[mt][nt][r]);
          }
    } else {
      u16* dst = VT + (size_t)(bb * Hn + h) * Dn * Tn;
#pragma unroll
      for (int mt = 0; mt < 4; mt++)
#pragma unroll
        for (int nt = 0; nt < 4; nt++) {
          const int t = t_base + mt * 16 + (quad << 2);
          const int d = nt * 16 + lo;
          ushort4 st;
          st.x = f2bf(acc[mt][nt][0]); st.y = f2bf(acc[mt][nt][1]);
          st.z = f2bf(acc[mt][nt][2]); st.w = f2bf(acc[mt][nt][3]);
          *(ushort4*)&dst[(size_t)d * Tn + t] = st;
        }
    }
  } else {
#pragma unroll
    for (int mt = 0; mt < 4; mt++)
#pragma unroll
      for (int nt = 0; nt < 4; nt++)
#pragma unroll
        for (int r = 0; r < 4; r++) {
          const int m = m0 + wm * 64 + mt * 16 + (quad << 2) + r;
          out[(size_t)m * Cn + n0 + wn * 64 + nt * 16 + lo] = acc[mt][nt][r];
        }
  }
}

// ---------------------------------------------------------------------------
// Causal flash attention on MFMA, dynamic LPT work-stealing.
// 512 blocks of 4 waves pull (q-tile,h,b) items longest-first from a device
// counter. Inner flash loop identical to R5 (verified).
// ---------------------------------------------------------------------------
#define KP 72   // LDS row pitch in u16 (144 B: 16B-aligned)

__global__ __launch_bounds__(256) void attn_kernel(const u16* __restrict__ Q,
                                                   const u16* __restrict__ K,
                                                   const u16* __restrict__ VT,
                                                   u16* __restrict__ O,
                                                   int* __restrict__ counter) {
  __shared__ u16 Ks[64 * KP];        // K-tile  [kv_row][d]
  __shared__ u16 Vt[64 * KP];        // V-tile  [d][kv_row]
  __shared__ u16 Pw[4][16 * KP];     // per-wave P round-trip [q_row][kv_row]
  __shared__ int s_item;

  const int tid = threadIdx.x;
  const int wv = tid >> 6, lane = tid & 63;
  const int lo = lane & 15, quad = lane >> 4;

  for (;;) {
    if (tid == 0) s_item = atomicAdd(counter, 1);
    __syncthreads();                 // broadcast item; also fences LDS reuse
    const int item = s_item;
    if (item >= NITEMS) return;      // uniform exit

    // LPT decode: longest q-tiles first
    const int q0 = (31 - item / 24) * 64;
    const int hb = item % 24;
    const int h = hb % 12, b = hb / 12;
    const size_t base = (size_t)(b * Hn + h) * Tn * Dn;   // Q/K [.,T,64]
    const size_t vtb  = (size_t)(b * Hn + h) * Dn * Tn;   // VT  [.,64,T]

    const u16* qp = Q + base + (size_t)(q0 + (wv << 4) + lo) * Dn + (quad << 3);
    const bf16x8 aq0 = *(const bf16x8*)qp;
    const bf16x8 aq1 = *(const bf16x8*)(qp + 32);

    f32x4 o[4] = {f32x4{0,0,0,0}, f32x4{0,0,0,0}, f32x4{0,0,0,0}, f32x4{0,0,0,0}};
    float m4[4] = {MASKVAL, MASKVAL, MASKVAL, MASKVAL};
    float l4[4] = {0.f, 0.f, 0.f, 0.f};

    for (int j0 = 0; j0 <= q0; j0 += 64) {
      __syncthreads();
      for (int c = tid; c < 512; c += 256) {
        const int r = c >> 3, cc = (c & 7) << 3;
        *(ushort8_t*)(&Ks[r * KP + cc]) =
            *(const ushort8_t*)(K + base + (size_t)(j0 + r) * Dn + cc);
        *(ushort8_t*)(&Vt[r * KP + cc]) =
            *(const ushort8_t*)(VT + vtb + (size_t)r * Tn + j0 + cc);
      }
      __syncthreads();

      f32x4 s[4];
#pragma unroll
      for (int nt = 0; nt < 4; nt++) {
        const bf16x8 bk0 = *(const bf16x8*)(&Ks[(nt * 16 + lo) * KP + (quad << 3)]);
        const bf16x8 bk1 = *(const bf16x8*)(&Ks[(nt * 16 + lo) * KP + 32 + (quad << 3)]);
        f32x4 a = {0.f, 0.f, 0.f, 0.f};
        a = __builtin_amdgcn_mfma_f32_16x16x32_bf16(aq0, bk0, a, 0, 0, 0);
        a = __builtin_amdgcn_mfma_f32_16x16x32_bf16(aq1, bk1, a, 0, 0, 0);
        s[nt] = a;
      }

      if (j0 == q0) {
#pragma unroll
        for (int nt = 0; nt < 4; nt++)
#pragma unroll
          for (int r = 0; r < 4; r++) {
            const int row = (wv << 4) + (quad << 2) + r;
            const int col = nt * 16 + lo;
            s[nt][r] = (col > row) ? MASKVAL : s[nt][r] * 0.125f;
          }
      } else {
#pragma unroll
        for (int nt = 0; nt < 4; nt++)
#pragma unroll
          for (int r = 0; r < 4; r++) s[nt][r] *= 0.125f;
      }

      float alpha[4];
#pragma unroll
      for (int r = 0; r < 4; r++) {
        float mx = fmaxf(fmaxf(s[0][r], s[1][r]), fmaxf(s[2][r], s[3][r]));
#pragma unroll
        for (int off = 1; off < 16; off <<= 1) mx = fmaxf(mx, __shfl_xor(mx, off));
        const float mnew = fmaxf(m4[r], mx);
        alpha[r] = safe_exp(m4[r] - mnew);
        m4[r] = mnew;
        float sum = 0.f;
#pragma unroll
        for (int nt = 0; nt < 4; nt++) {
          const float p = safe_exp(s[nt][r] - mnew);
          s[nt][r] = p;
          sum += p;
        }
#pragma unroll
        for (int off = 1; off < 16; off <<= 1) sum += __shfl_xor(sum, off);
        l4[r] = l4[r] * alpha[r] + sum;
      }

      u16* pw = Pw[wv];
#pragma unroll
      for (int nt = 0; nt < 4; nt++)
#pragma unroll
        for (int r = 0; r < 4; r++)
          pw[((quad << 2) + r) * KP + nt * 16 + lo] = f2bf(s[nt][r]);
      const bf16x8 pa0 = *(const bf16x8*)(&pw[lo * KP + (quad << 3)]);
      const bf16x8 pa1 = *(const bf16x8*)(&pw[lo * KP + 32 + (quad << 3)]);

#pragma unroll
      for (int nt = 0; nt < 4; nt++) {
#pragma unroll
        for (int r = 0; r < 4; r++) o[nt][r] *= alpha[r];
        const bf16x8 bv0 = *(const bf16x8*)(&Vt[(nt * 16 + lo) * KP + (quad << 3)]);
        const bf16x8 bv1 = *(const bf16x8*)(&Vt[(nt * 16 + lo) * KP + 32 + (quad << 3)]);
        o[nt] = __builtin_amdgcn_mfma_f32_16x16x32_bf16(pa0, bv0, o[nt], 0, 0, 0);
        o[nt] = __builtin_amdgcn_mfma_f32_16x16x32_bf16(pa1, bv1, o[nt], 0, 0, 0);
      }
    }

    float inv[4];
#pragma unroll
    for (int r = 0; r < 4; r++) inv[r] = 1.f / l4[r];
#pragma unroll
    for (int nt = 0; nt < 4; nt++)
#pragma unroll
      for (int r = 0; r < 4; r++) {
        const int row = q0 + (wv << 4) + (quad << 2) + r;
        const int col = h * 64 + nt * 16 + lo;
        O[(size_t)(b * Tn + row) * Cn + col] = f2bf(o[nt][r] * inv[r]);
      }
  }
}

// ---------------------------------------------------------------------------
extern "C" void kernel_launch(void* const* d_in, const int* in_sizes, int n_in,
                              void* d_out, int out_size, void* d_ws, size_t ws_size,
                              hipStream_t stream) {
  const float* x    = (const float*)d_in[0];   // [B,T,C] fp32
  const float* Wqkv = (const float*)d_in[1];   // [C,3C] fp32
  const float* Wout = (const float*)d_in[2];   // [C,C] fp32
  float* out = (float*)d_out;                  // [B,T,C] fp32

  const size_t per = (size_t)Bn * Hn * Tn * Dn;     // 3,145,728 elems
  u16* xb    = (u16*)d_ws;                          // [4096,768] bf16
  u16* WqkvT = xb + (size_t)Mn * Cn;                // [2304,768] bf16
  u16* WoutT = WqkvT + (size_t)N3n * Cn;            // [768,768]  bf16
  u16* Qb    = WoutT + (size_t)Cn * Cn;             // [B,H,T,DH] bf16
  u16* Kb    = Qb + per;                            // [B,H,T,DH] bf16
  u16* VTb   = Kb + per;                            // [B,H,DH,T] bf16
  u16* attn  = VTb + per;                           // [B,T,C]    bf16
  int* counter = (int*)(attn + (size_t)Mn * Cn);    // 4 B, 4-aligned
  // total ws use: ~36.2 MB + 4 B (< 50.3 MB available)

  cast_bf16<<<(Mn * Cn) / 1024, 256, 0, stream>>>(x, xb, counter);
  transpose_cast<<<dim3(N3n / 32, Cn / 32), dim3(32, 8), 0, stream>>>(Wqkv, WqkvT, Cn, N3n);
  transpose_cast<<<dim3(Cn / 32, Cn / 32), dim3(32, 8), 0, stream>>>(Wout, WoutT, Cn, Cn);

  mfma_gemm<0><<<dim3(N3n / 128, Mn / 128), 256, 0, stream>>>(xb, WqkvT, Qb, Kb, VTb, nullptr);
  attn_kernel<<<dim3(512), 256, 0, stream>>>(Qb, Kb, VTb, attn, counter);
  mfma_gemm<1><<<dim3(Cn / 128, Mn / 128), 256, 0, stream>>>(attn, WoutT, nullptr, nullptr, nullptr, out);
}